// Round 1
// baseline (1464.114 us; speedup 1.0000x reference)
//
#include <hip/hip_runtime.h>
#include <hip/hip_bf16.h>

// Clockwork RNN, hierarchical decomposition.
// Modules j=7..0: module j updates at t % 2^j == 0 and reads only modules >= j.
// Phase order: P7, U6, P6, U5, ..., U0, P0, then output assembly.
// xwb (= xW + bh, active rows only) lives in d_out's memory (overwritten at the end).
// Compact per-module trajectories Hmod[j] : [T>>j][B][H] live in d_ws (33.4 MB).

#define TT 256
#define BB 128
#define INW 512
#define HH 128
#define MM 8
#define MHW 1024

// Hmod offsets in floats: cumulative (sum of T>>i for i<j) * B*H
__constant__ unsigned int c_hmod_off[8] = {
    0u, 4194304u, 6291456u, 7340032u, 7864320u, 8126464u, 8257536u, 8323072u};

__device__ __forceinline__ int active_thr(int t) {
    int ma = (t == 0) ? 8 : min(__ffs(t), 8);
    return ma * HH;
}

// ---------------------------------------------------------------------------
// K_xw: xwb[t][b][r] = sum_i x[t][b][i] * Wxh[r][i] + bh[r]   for r < thr(t)
// grid: (16 row-tiles, 2 batch-tiles, 256 t), block 256
// ---------------------------------------------------------------------------
__global__ __launch_bounds__(256) void k_xw(const float* __restrict__ x,
                                            const float* __restrict__ Wxh,
                                            const float* __restrict__ bh,
                                            float* __restrict__ xwb) {
    int t = blockIdx.z;
    int thr = active_thr(t);
    int r0 = blockIdx.x * 64;
    if (r0 >= thr) return;
    int b0 = blockIdx.y * 64;

    __shared__ float sW[64][33];
    __shared__ float sX[64][33];
    int tid = threadIdx.x;
    int tx = tid & 15, ty = tid >> 4;
    float acc[4][4] = {};  // [bi][ri]

    for (int k0 = 0; k0 < INW; k0 += 32) {
#pragma unroll
        for (int i = 0; i < 8; ++i) {
            int l = i * 256 + tid;
            int rr = l >> 5, kk = l & 31;
            sW[rr][kk] = Wxh[(r0 + rr) * INW + k0 + kk];
            sX[rr][kk] = x[(t * BB + b0 + rr) * INW + k0 + kk];
        }
        __syncthreads();
#pragma unroll
        for (int kk = 0; kk < 32; ++kk) {
            float wv[4], xv[4];
#pragma unroll
            for (int i = 0; i < 4; ++i) wv[i] = sW[ty * 4 + i][kk];
#pragma unroll
            for (int i = 0; i < 4; ++i) xv[i] = sX[tx * 4 + i][kk];
#pragma unroll
            for (int bi = 0; bi < 4; ++bi)
#pragma unroll
                for (int ri = 0; ri < 4; ++ri) acc[bi][ri] += xv[bi] * wv[ri];
        }
        __syncthreads();
    }
    int rbase = r0 + ty * 4;
    float bias[4];
#pragma unroll
    for (int ri = 0; ri < 4; ++ri) bias[ri] = bh[rbase + ri];
#pragma unroll
    for (int bi = 0; bi < 4; ++bi) {
        int b = b0 + tx * 4 + bi;
        float4 v = make_float4(acc[bi][0] + bias[0], acc[bi][1] + bias[1],
                               acc[bi][2] + bias[2], acc[bi][3] + bias[3]);
        *reinterpret_cast<float4*>(&xwb[(size_t)(t * BB + b) * MHW + rbase]) = v;
    }
}

// ---------------------------------------------------------------------------
// K_u: for module mi, update index k (t = k<<mi):
//   xwb[t][b][mi*H + r] += sum_{j>mi} sum_c h_j_src[b][c] * Whh[mi*H+r][j*H+c]
// h_j_src = h_prev cols (k==0) else Hmod[j][ (t-1)>>j ]
// grid: (T>>mi, 4 tiles), block 256
// ---------------------------------------------------------------------------
__global__ __launch_bounds__(256) void k_u(const float* __restrict__ Whh,
                                           const float* __restrict__ hprev,
                                           const float* __restrict__ hmod,
                                           float* __restrict__ xwb, int mi) {
    int k = blockIdx.x;
    int tile = blockIdx.y;
    int r0 = (tile >> 1) * 64, b0 = (tile & 1) * 64;
    int t = k << mi;

    __shared__ float sA[64][33];
    __shared__ float sH[64][33];
    int tid = threadIdx.x;
    int tx = tid & 15, ty = tid >> 4;
    float acc[4][4] = {};  // [bi][ri]

    for (int j = mi + 1; j < 8; ++j) {
        const float* src;
        int stride;
        if (k == 0) {
            src = hprev + j * HH;  // [b][c], row stride MH
            stride = MHW;
        } else {
            int g = (t - 1) >> j;
            src = hmod + c_hmod_off[j] + (size_t)g * BB * HH;  // [b][c], stride H
            stride = HH;
        }
        for (int c0 = 0; c0 < HH; c0 += 32) {
#pragma unroll
            for (int i = 0; i < 8; ++i) {
                int l = i * 256 + tid;
                int rr = l >> 5, cc = l & 31;
                sA[rr][cc] = Whh[(size_t)(mi * HH + r0 + rr) * MHW + j * HH + c0 + cc];
                sH[rr][cc] = src[(size_t)(b0 + rr) * stride + c0 + cc];
            }
            __syncthreads();
#pragma unroll
            for (int cc = 0; cc < 32; ++cc) {
                float av[4], hv[4];
#pragma unroll
                for (int i = 0; i < 4; ++i) av[i] = sA[ty * 4 + i][cc];
#pragma unroll
                for (int i = 0; i < 4; ++i) hv[i] = sH[tx * 4 + i][cc];
#pragma unroll
                for (int bi = 0; bi < 4; ++bi)
#pragma unroll
                    for (int ri = 0; ri < 4; ++ri) acc[bi][ri] += hv[bi] * av[ri];
            }
            __syncthreads();
        }
    }
    int rbase = mi * HH + r0 + ty * 4;
#pragma unroll
    for (int bi = 0; bi < 4; ++bi) {
        int b = b0 + tx * 4 + bi;
        float4* p = reinterpret_cast<float4*>(&xwb[(size_t)(t * BB + b) * MHW + rbase]);
        float4 v = *p;
        v.x += acc[bi][0];
        v.y += acc[bi][1];
        v.z += acc[bi][2];
        v.w += acc[bi][3];
        *p = v;
    }
}

// ---------------------------------------------------------------------------
// K_phase: sequential scan for module mi, one block per batch, no grid sync.
//   h = A_mi,mi @ h + u_k ;  Hmod[mi][k][b][:] = h
// grid: 128 blocks, block 256 (2 threads per output row, K split 64/64)
// ---------------------------------------------------------------------------
__global__ __launch_bounds__(256) void k_phase(const float* __restrict__ Whh,
                                               const float* __restrict__ hprev,
                                               const float* __restrict__ xwb,
                                               float* __restrict__ hmod, int mi) {
    int b = blockIdx.x;
    int tid = threadIdx.x;
    __shared__ float sA[128 * 129];
    __shared__ float sh[128];
    __shared__ float part[256];

#pragma unroll
    for (int i = 0; i < 64; ++i) {
        int l = i * 256 + tid;
        int rr = l >> 7, cc = l & 127;
        sA[rr * 129 + cc] = Whh[(size_t)(mi * HH + rr) * MHW + mi * HH + cc];
    }
    if (tid < 128) sh[tid] = hprev[(size_t)b * MHW + mi * HH + tid];
    __syncthreads();

    int Tm = TT >> mi;
    int r = tid & 127, half = tid >> 7;
    int c0 = half * 64;
    float* hout = hmod + c_hmod_off[mi];

    for (int k = 0; k < Tm; ++k) {
        int t = k << mi;
        float u = 0.f;
        if (tid < 128) u = xwb[(size_t)(t * BB + b) * MHW + mi * HH + tid];
        float a0 = 0.f, a1 = 0.f, a2 = 0.f, a3 = 0.f;
#pragma unroll
        for (int cc = 0; cc < 64; cc += 4) {
            a0 += sA[r * 129 + c0 + cc] * sh[c0 + cc];
            a1 += sA[r * 129 + c0 + cc + 1] * sh[c0 + cc + 1];
            a2 += sA[r * 129 + c0 + cc + 2] * sh[c0 + cc + 2];
            a3 += sA[r * 129 + c0 + cc + 3] * sh[c0 + cc + 3];
        }
        part[tid] = (a0 + a1) + (a2 + a3);
        __syncthreads();
        if (tid < 128) {
            float hn = part[tid] + part[tid + 128] + u;
            hout[((size_t)k * BB + b) * HH + tid] = hn;
            sh[tid] = hn;
        }
        __syncthreads();
    }
}

// ---------------------------------------------------------------------------
// K_out: out[t][b][j*H + h] = Hmod[j][t>>j][b][h]; also h_last for t==T-1
// grid: (128 b, 256 t), block 256, one float4 per thread
// ---------------------------------------------------------------------------
__global__ __launch_bounds__(256) void k_out(const float* __restrict__ hmod,
                                             float* __restrict__ out) {
    int b = blockIdx.x, t = blockIdx.y;
    int tid = threadIdx.x;
    int i = tid * 4;
    int j = i >> 7;
    int k = t >> j;
    const float4 v = *reinterpret_cast<const float4*>(
        &hmod[c_hmod_off[j] + ((size_t)k * BB + b) * HH + (i & 127)]);
    *reinterpret_cast<float4*>(&out[((size_t)t * BB + b) * MHW + i]) = v;
    if (t == TT - 1) {
        *reinterpret_cast<float4*>(
            &out[(size_t)TT * BB * MHW + (size_t)b * MHW + i]) = v;
    }
}

// ---------------------------------------------------------------------------
extern "C" void kernel_launch(void* const* d_in, const int* in_sizes, int n_in,
                              void* d_out, int out_size, void* d_ws, size_t ws_size,
                              hipStream_t stream) {
    const float* x = (const float*)d_in[0];
    const float* hprev = (const float*)d_in[1];
    const float* Wxh = (const float*)d_in[2];
    const float* Whh = (const float*)d_in[3];
    const float* bh = (const float*)d_in[4];
    float* out = (float*)d_out;

    float* xwb = out;             // reuse output buffer as scratch for xW + bh + u
    float* hmod = (float*)d_ws;   // 510 * B * H floats = 33.4 MB

    k_xw<<<dim3(16, 2, 256), 256, 0, stream>>>(x, Wxh, bh, xwb);

    for (int mi = 7; mi >= 0; --mi) {
        int Tm = TT >> mi;
        if (mi < 7)
            k_u<<<dim3(Tm, 4), 256, 0, stream>>>(Whh, hprev, hmod, xwb, mi);
        k_phase<<<128, 256, 0, stream>>>(Whh, hprev, xwb, hmod, mi);
    }

    k_out<<<dim3(128, 256), 256, 0, stream>>>(hmod, out);
}

// Round 2
// 861.826 us; speedup vs baseline: 1.6989x; 1.6989x over previous
//
#include <hip/hip_runtime.h>
#include <hip/hip_bf16.h>

// Clockwork RNN, hierarchical decomposition + bf16 MFMA GEMMs.
// Modules j=7..0: module j updates at t % 2^j == 0 and reads only modules >= j.
// Order: k_xw (all t), then per mi=7..0: {k_u (mi<7), k_phase}, then k_out.
// xwb (= xW + bh + inter-module u) lives in d_out's memory (overwritten at end).
// Compact trajectories Hmod[j] : [T>>j][B][H] in d_ws (33.4 MB).

#define TT 256
#define BB 128
#define INW 512
#define HH 128
#define MHW 1024

typedef __bf16 bf16x8 __attribute__((ext_vector_type(8)));
typedef float f32x4 __attribute__((ext_vector_type(4)));

__constant__ unsigned int c_hmod_off[8] = {
    0u, 4194304u, 6291456u, 7340032u, 7864320u, 8126464u, 8257536u, 8323072u};

__device__ __forceinline__ int active_thr(int t) {
    int ma = (t == 0) ? 8 : min(__ffs(t), 8);
    return ma * HH;
}

__device__ __forceinline__ unsigned short f2bf(float f) {
    union { float f; unsigned int u; } v{f};
    unsigned int r = v.u + 0x7FFFu + ((v.u >> 16) & 1u);  // RNE
    return (unsigned short)(r >> 16);
}

// Stage a [128 rows][64 k] f32 source tile into LDS as bf16 with XOR swizzle.
// dst: 16 KB LDS region. 256 threads, 8 passes of 16 rows.
__device__ __forceinline__ void stage_tile(char* dst, const float* __restrict__ src,
                                           size_t stride, int tid) {
    int k4 = (tid & 15) * 4;
#pragma unroll
    for (int p = 0; p < 8; ++p) {
        int row = p * 16 + (tid >> 4);
        float4 v = *reinterpret_cast<const float4*>(src + (size_t)row * stride + k4);
        ushort4 b;
        b.x = f2bf(v.x); b.y = f2bf(v.y); b.z = f2bf(v.z); b.w = f2bf(v.w);
        int off = (row * 128 + k4 * 2) ^ ((row & 7) << 4);
        *reinterpret_cast<ushort4*>(dst + off) = b;
    }
}

// Read one 16x32 bf16 A/B fragment (8 bf16, contiguous-in-k) from swizzled tile.
__device__ __forceinline__ bf16x8 frag_ld(const char* tile, int row, int ks, int lane) {
    int off = (row * 128 + ks * 64 + (lane >> 4) * 16) ^ ((row & 7) << 4);
    return *reinterpret_cast<const bf16x8*>(tile + off);
}

// ---------------------------------------------------------------------------
// K_xw (MFMA): xwb[t][b][mi*H + r] = sum_i x[t][b][i]*Wxh[mi*H+r][i] + bh[...]
// grid: (8 mi, 256 t), block 256 (4 waves, each 64x64 of the 128x128 tile)
// ---------------------------------------------------------------------------
__global__ __launch_bounds__(256) void k_xw(const float* __restrict__ x,
                                            const float* __restrict__ Wxh,
                                            const float* __restrict__ bh,
                                            float* __restrict__ xwb) {
    int mi = blockIdx.x, t = blockIdx.y;
    if (mi * HH >= active_thr(t)) return;

    __shared__ char lds[2 * 128 * 128];
    char* sW = lds;
    char* sX = lds + 128 * 128;
    int tid = threadIdx.x, lane = tid & 63, wid = tid >> 6;
    int wr = (wid >> 1) * 64, wc = (wid & 1) * 64;

    f32x4 acc[4][4] = {};
    const float* Wbase = Wxh + (size_t)(mi * HH) * INW;
    const float* Xbase = x + (size_t)t * BB * INW;

    for (int k0 = 0; k0 < INW; k0 += 64) {
        stage_tile(sW, Wbase + k0, INW, tid);
        stage_tile(sX, Xbase + k0, INW, tid);
        __syncthreads();
#pragma unroll
        for (int ks = 0; ks < 2; ++ks) {
            bf16x8 fa[4], fb[4];
#pragma unroll
            for (int i = 0; i < 4; ++i) {
                fa[i] = frag_ld(sW, wr + i * 16 + (lane & 15), ks, lane);
                fb[i] = frag_ld(sX, wc + i * 16 + (lane & 15), ks, lane);
            }
#pragma unroll
            for (int i = 0; i < 4; ++i)
#pragma unroll
                for (int j = 0; j < 4; ++j)
                    acc[i][j] = __builtin_amdgcn_mfma_f32_16x16x32_bf16(
                        fa[i], fb[j], acc[i][j], 0, 0, 0);
        }
        __syncthreads();
    }
    // D layout: col(b) = lane&15, row(r) = (lane>>4)*4 + reg
#pragma unroll
    for (int i = 0; i < 4; ++i) {
        int rbase = wr + i * 16 + (lane >> 4) * 4;
        float4 bias = *reinterpret_cast<const float4*>(&bh[mi * HH + rbase]);
#pragma unroll
        for (int j = 0; j < 4; ++j) {
            int b = wc + j * 16 + (lane & 15);
            float4 v = make_float4(acc[i][j][0] + bias.x, acc[i][j][1] + bias.y,
                                   acc[i][j][2] + bias.z, acc[i][j][3] + bias.w);
            *reinterpret_cast<float4*>(
                &xwb[(size_t)(t * BB + b) * MHW + mi * HH + rbase]) = v;
        }
    }
}

// ---------------------------------------------------------------------------
// K_u (MFMA): xwb[t][b][mi*H+r] += sum_{j>mi} Whh[mi*H+r][j*H+c] * h_j[b][c]
// grid: (T>>mi), block 256. t = k<<mi. h_j = hprev (k==0) else Hmod[j][(t-1)>>j]
// ---------------------------------------------------------------------------
__global__ __launch_bounds__(256) void k_u(const float* __restrict__ Whh,
                                           const float* __restrict__ hprev,
                                           const float* __restrict__ hmod,
                                           float* __restrict__ xwb, int mi) {
    int k = blockIdx.x;
    int t = k << mi;
    __shared__ char lds[2 * 128 * 128];
    char* sA = lds;
    char* sH = lds + 128 * 128;
    int tid = threadIdx.x, lane = tid & 63, wid = tid >> 6;
    int wr = (wid >> 1) * 64, wc = (wid & 1) * 64;

    f32x4 acc[4][4] = {};

    for (int j = mi + 1; j < 8; ++j) {
        const float* src;
        size_t stride;
        if (k == 0) {
            src = hprev + j * HH;
            stride = MHW;
        } else {
            int g = (t - 1) >> j;
            src = hmod + c_hmod_off[j] + (size_t)g * BB * HH;
            stride = HH;
        }
        const float* Abase = Whh + (size_t)(mi * HH) * MHW + j * HH;
#pragma unroll
        for (int c0 = 0; c0 < HH; c0 += 64) {
            stage_tile(sA, Abase + c0, MHW, tid);
            stage_tile(sH, src + c0, stride, tid);
            __syncthreads();
#pragma unroll
            for (int ks = 0; ks < 2; ++ks) {
                bf16x8 fa[4], fb[4];
#pragma unroll
                for (int i = 0; i < 4; ++i) {
                    fa[i] = frag_ld(sA, wr + i * 16 + (lane & 15), ks, lane);
                    fb[i] = frag_ld(sH, wc + i * 16 + (lane & 15), ks, lane);
                }
#pragma unroll
                for (int i = 0; i < 4; ++i)
#pragma unroll
                    for (int jj = 0; jj < 4; ++jj)
                        acc[i][jj] = __builtin_amdgcn_mfma_f32_16x16x32_bf16(
                            fa[i], fb[jj], acc[i][jj], 0, 0, 0);
            }
            __syncthreads();
        }
    }
#pragma unroll
    for (int i = 0; i < 4; ++i) {
        int rbase = wr + i * 16 + (lane >> 4) * 4;
#pragma unroll
        for (int j = 0; j < 4; ++j) {
            int b = wc + j * 16 + (lane & 15);
            float4* p = reinterpret_cast<float4*>(
                &xwb[(size_t)(t * BB + b) * MHW + mi * HH + rbase]);
            float4 v = *p;
            v.x += acc[i][j][0]; v.y += acc[i][j][1];
            v.z += acc[i][j][2]; v.w += acc[i][j][3];
            *p = v;
        }
    }
}

// ---------------------------------------------------------------------------
// K_phase: serial scan for module mi, one block per batch, A in registers.
// 128 threads; thread r holds full A row (128 VGPRs); double-buffered sh.
// ---------------------------------------------------------------------------
__global__ __launch_bounds__(128) void k_phase(const float* __restrict__ Whh,
                                               const float* __restrict__ hprev,
                                               const float* __restrict__ xwb,
                                               float* __restrict__ hmod, int mi) {
    int b = blockIdx.x;
    int r = threadIdx.x;
    __shared__ float sh[2][128];
    float A[128];
    const float* wrow = &Whh[(size_t)(mi * HH + r) * MHW + mi * HH];
#pragma unroll
    for (int c = 0; c < 128; c += 4) {
        float4 v = *reinterpret_cast<const float4*>(wrow + c);
        A[c] = v.x; A[c + 1] = v.y; A[c + 2] = v.z; A[c + 3] = v.w;
    }
    sh[0][r] = hprev[(size_t)b * MHW + mi * HH + r];
    __syncthreads();

    int Tm = TT >> mi;
    float* hout = hmod + c_hmod_off[mi];
    float u_next = xwb[(size_t)b * MHW + mi * HH + r];  // t=0
    for (int k = 0; k < Tm; ++k) {
        int cur = k & 1;
        float u = u_next;
        if (k + 1 < Tm) {
            int t1 = (k + 1) << mi;
            u_next = xwb[(size_t)(t1 * BB + b) * MHW + mi * HH + r];
        }
        float a0 = 0.f, a1 = 0.f, a2 = 0.f, a3 = 0.f;
#pragma unroll
        for (int c = 0; c < 128; c += 4) {
            a0 += A[c] * sh[cur][c];
            a1 += A[c + 1] * sh[cur][c + 1];
            a2 += A[c + 2] * sh[cur][c + 2];
            a3 += A[c + 3] * sh[cur][c + 3];
        }
        float hn = (a0 + a1) + (a2 + a3) + u;
        hout[((size_t)k * BB + b) * HH + r] = hn;
        sh[cur ^ 1][r] = hn;
        __syncthreads();
    }
}

// ---------------------------------------------------------------------------
// K_out: out[t][b][j*H + h] = Hmod[j][t>>j][b][h]; h_last for t==T-1
// ---------------------------------------------------------------------------
__global__ __launch_bounds__(256) void k_out(const float* __restrict__ hmod,
                                             float* __restrict__ out) {
    int b = blockIdx.x, t = blockIdx.y;
    int tid = threadIdx.x;
    int i = tid * 4;
    int j = i >> 7;
    int k = t >> j;
    const float4 v = *reinterpret_cast<const float4*>(
        &hmod[c_hmod_off[j] + ((size_t)k * BB + b) * HH + (i & 127)]);
    *reinterpret_cast<float4*>(&out[((size_t)t * BB + b) * MHW + i]) = v;
    if (t == TT - 1) {
        *reinterpret_cast<float4*>(
            &out[(size_t)TT * BB * MHW + (size_t)b * MHW + i]) = v;
    }
}

// ---------------------------------------------------------------------------
extern "C" void kernel_launch(void* const* d_in, const int* in_sizes, int n_in,
                              void* d_out, int out_size, void* d_ws, size_t ws_size,
                              hipStream_t stream) {
    const float* x = (const float*)d_in[0];
    const float* hprev = (const float*)d_in[1];
    const float* Wxh = (const float*)d_in[2];
    const float* Whh = (const float*)d_in[3];
    const float* bh = (const float*)d_in[4];
    float* out = (float*)d_out;

    float* xwb = out;            // scratch: xW + bh + u, overwritten by k_out
    float* hmod = (float*)d_ws;  // 8,355,840 floats = 33.4 MB

    k_xw<<<dim3(8, 256), 256, 0, stream>>>(x, Wxh, bh, xwb);

    for (int mi = 7; mi >= 0; --mi) {
        int Tm = TT >> mi;
        if (mi < 7)
            k_u<<<dim3(Tm), 256, 0, stream>>>(Whh, hprev, hmod, xwb, mi);
        k_phase<<<128, 128, 0, stream>>>(Whh, hprev, xwb, hmod, mi);
    }

    k_out<<<dim3(128, 256), 256, 0, stream>>>(hmod, out);
}

// Round 3
// 608.227 us; speedup vs baseline: 2.4072x; 1.4169x over previous
//
#include <hip/hip_runtime.h>
#include <hip/hip_bf16.h>

// Clockwork RNN, hierarchical decomposition + bf16 MFMA GEMMs.
// Round 3: batched staging loads (register array forces issue of all 16
// global loads) + double-buffered LDS with T14 ordering
// {barrier; issue loads(t+1); MFMA(t); convert+write(t+1)}.

#define TT 256
#define BB 128
#define INW 512
#define HH 128
#define MHW 1024

typedef __bf16 bf16x8 __attribute__((ext_vector_type(8)));
typedef float f32x4 __attribute__((ext_vector_type(4)));

__constant__ unsigned int c_hmod_off[8] = {
    0u, 4194304u, 6291456u, 7340032u, 7864320u, 8126464u, 8257536u, 8323072u};

__device__ __forceinline__ int active_thr(int t) {
    int ma = (t == 0) ? 8 : min(__ffs(t), 8);
    return ma * HH;
}

__device__ __forceinline__ unsigned short f2bf(float f) {
    union { float f; unsigned int u; } v{f};
    unsigned int r = v.u + 0x7FFFu + ((v.u >> 16) & 1u);  // RNE
    return (unsigned short)(r >> 16);
}

#define TILE_B 16384  // one [128 rows][64 k] bf16 tile image in LDS

// Batch-load a [128][64] f32 tile: 8 independent float4 per thread.
__device__ __forceinline__ void stage_load(float4 (&v)[8],
                                           const float* __restrict__ src,
                                           int stride, int tid) {
    int k4 = (tid & 15) * 4;
    int r0 = tid >> 4;
#pragma unroll
    for (int p = 0; p < 8; ++p)
        v[p] = *reinterpret_cast<const float4*>(src + (size_t)(p * 16 + r0) * stride + k4);
}

// Convert + write the staged tile into LDS (bf16, XOR-swizzled rows).
__device__ __forceinline__ void stage_write(char* dst, const float4 (&v)[8], int tid) {
    int k8 = (tid & 15) * 8;  // byte offset of this thread's 4 bf16
    int r0 = tid >> 4;
#pragma unroll
    for (int p = 0; p < 8; ++p) {
        int row = p * 16 + r0;
        ushort4 b;
        b.x = f2bf(v[p].x); b.y = f2bf(v[p].y);
        b.z = f2bf(v[p].z); b.w = f2bf(v[p].w);
        int off = (row * 128 + k8) ^ ((row & 7) << 4);
        *reinterpret_cast<ushort4*>(dst + off) = b;
    }
}

// Read one 16x32 bf16 fragment (8 bf16) from a swizzled tile.
__device__ __forceinline__ bf16x8 frag_ld(const char* tile, int row, int ks, int lane) {
    int off = (row * 128 + ks * 64 + (lane >> 4) * 16) ^ ((row & 7) << 4);
    return *reinterpret_cast<const bf16x8*>(tile + off);
}

// 128x128x64 MFMA block: A-tile x B-tile -> acc
__device__ __forceinline__ void mfma_tile(const char* sA, const char* sB,
                                          f32x4 (&acc)[4][4], int lane,
                                          int wr, int wc) {
#pragma unroll
    for (int ks = 0; ks < 2; ++ks) {
        bf16x8 fa[4], fb[4];
#pragma unroll
        for (int i = 0; i < 4; ++i) {
            fa[i] = frag_ld(sA, wr + i * 16 + (lane & 15), ks, lane);
            fb[i] = frag_ld(sB, wc + i * 16 + (lane & 15), ks, lane);
        }
#pragma unroll
        for (int i = 0; i < 4; ++i)
#pragma unroll
            for (int j = 0; j < 4; ++j)
                acc[i][j] = __builtin_amdgcn_mfma_f32_16x16x32_bf16(
                    fa[i], fb[j], acc[i][j], 0, 0, 0);
    }
}

// ---------------------------------------------------------------------------
// K_xw: xwb[t][b][mi*H + r] = sum_i x[t][b][i]*Wxh[mi*H+r][i] + bh[...]
// grid (8 mi, 256 t), block 256 (4 waves, 64x64 quadrants of 128x128 tile)
// ---------------------------------------------------------------------------
__global__ __launch_bounds__(256) void k_xw(const float* __restrict__ x,
                                            const float* __restrict__ Wxh,
                                            const float* __restrict__ bh,
                                            float* __restrict__ xwb) {
    int mi = blockIdx.x, t = blockIdx.y;
    if (mi * HH >= active_thr(t)) return;

    __shared__ char lds[4 * TILE_B];  // W0 X0 | W1 X1
    int tid = threadIdx.x, lane = tid & 63, wid = tid >> 6;
    int wr = (wid >> 1) * 64, wc = (wid & 1) * 64;
    const float* Wbase = Wxh + (size_t)(mi * HH) * INW;
    const float* Xbase = x + (size_t)t * BB * INW;

    f32x4 acc[4][4] = {};
    float4 vW[8], vX[8];
    stage_load(vW, Wbase, INW, tid);
    stage_load(vX, Xbase, INW, tid);
    stage_write(lds, vW, tid);
    stage_write(lds + TILE_B, vX, tid);

    for (int it = 0; it < 8; ++it) {
        int cur = it & 1;
        __syncthreads();
        if (it < 7) {
            stage_load(vW, Wbase + (it + 1) * 64, INW, tid);
            stage_load(vX, Xbase + (it + 1) * 64, INW, tid);
        }
        mfma_tile(lds + cur * 2 * TILE_B, lds + cur * 2 * TILE_B + TILE_B,
                  acc, lane, wr, wc);
        if (it < 7) {
            stage_write(lds + (cur ^ 1) * 2 * TILE_B, vW, tid);
            stage_write(lds + (cur ^ 1) * 2 * TILE_B + TILE_B, vX, tid);
        }
    }
    // D layout: col(b) = lane&15, row(r) = (lane>>4)*4 + reg
#pragma unroll
    for (int i = 0; i < 4; ++i) {
        int rbase = wr + i * 16 + (lane >> 4) * 4;
        float4 bias = *reinterpret_cast<const float4*>(&bh[mi * HH + rbase]);
#pragma unroll
        for (int j = 0; j < 4; ++j) {
            int b = wc + j * 16 + (lane & 15);
            float4 v = make_float4(acc[i][j][0] + bias.x, acc[i][j][1] + bias.y,
                                   acc[i][j][2] + bias.z, acc[i][j][3] + bias.w);
            *reinterpret_cast<float4*>(
                &xwb[(size_t)(t * BB + b) * MHW + mi * HH + rbase]) = v;
        }
    }
}

// ---------------------------------------------------------------------------
// K_u: xwb[t][b][mi*H+r] += sum_{j>mi} Whh[mi*H+r][j*H+c] * h_j[b][c]
// grid (T>>mi), block 256. t = k<<mi. Flat tile loop over (j, c0) pairs.
// ---------------------------------------------------------------------------
__global__ __launch_bounds__(256) void k_u(const float* __restrict__ Whh,
                                           const float* __restrict__ hprev,
                                           const float* __restrict__ hmod,
                                           float* __restrict__ xwb, int mi) {
    int k = blockIdx.x;
    int t = k << mi;
    __shared__ char lds[4 * TILE_B];  // A0 H0 | A1 H1
    int tid = threadIdx.x, lane = tid & 63, wid = tid >> 6;
    int wr = (wid >> 1) * 64, wc = (wid & 1) * 64;

    int ntile = 2 * (7 - mi);
    auto srcs = [&](int tt, const float*& pa, const float*& ph, int& hstr) {
        int j = mi + 1 + (tt >> 1);
        int c0 = (tt & 1) * 64;
        pa = Whh + (size_t)(mi * HH) * MHW + j * HH + c0;
        if (k == 0) {
            ph = hprev + j * HH + c0;
            hstr = MHW;
        } else {
            int g = (t - 1) >> j;
            ph = hmod + c_hmod_off[j] + (size_t)g * BB * HH + c0;
            hstr = HH;
        }
    };

    f32x4 acc[4][4] = {};
    float4 vA[8], vH[8];
    const float *pa, *ph;
    int hstr;
    srcs(0, pa, ph, hstr);
    stage_load(vA, pa, MHW, tid);
    stage_load(vH, ph, hstr, tid);
    stage_write(lds, vA, tid);
    stage_write(lds + TILE_B, vH, tid);

    for (int tt = 0; tt < ntile; ++tt) {
        int cur = tt & 1;
        __syncthreads();
        if (tt + 1 < ntile) {
            srcs(tt + 1, pa, ph, hstr);
            stage_load(vA, pa, MHW, tid);
            stage_load(vH, ph, hstr, tid);
        }
        mfma_tile(lds + cur * 2 * TILE_B, lds + cur * 2 * TILE_B + TILE_B,
                  acc, lane, wr, wc);
        if (tt + 1 < ntile) {
            stage_write(lds + (cur ^ 1) * 2 * TILE_B, vA, tid);
            stage_write(lds + (cur ^ 1) * 2 * TILE_B + TILE_B, vH, tid);
        }
    }
#pragma unroll
    for (int i = 0; i < 4; ++i) {
        int rbase = wr + i * 16 + (lane >> 4) * 4;
#pragma unroll
        for (int j = 0; j < 4; ++j) {
            int b = wc + j * 16 + (lane & 15);
            float4* p = reinterpret_cast<float4*>(
                &xwb[(size_t)(t * BB + b) * MHW + mi * HH + rbase]);
            float4 v = *p;
            v.x += acc[i][j][0]; v.y += acc[i][j][1];
            v.z += acc[i][j][2]; v.w += acc[i][j][3];
            *p = v;
        }
    }
}

// ---------------------------------------------------------------------------
// K_phase: serial scan for module mi, one block per batch, A in registers.
// ---------------------------------------------------------------------------
__global__ __launch_bounds__(128) void k_phase(const float* __restrict__ Whh,
                                               const float* __restrict__ hprev,
                                               const float* __restrict__ xwb,
                                               float* __restrict__ hmod, int mi) {
    int b = blockIdx.x;
    int r = threadIdx.x;
    __shared__ float sh[2][128];
    float A[128];
    const float* wrow = &Whh[(size_t)(mi * HH + r) * MHW + mi * HH];
#pragma unroll
    for (int c = 0; c < 128; c += 4) {
        float4 v = *reinterpret_cast<const float4*>(wrow + c);
        A[c] = v.x; A[c + 1] = v.y; A[c + 2] = v.z; A[c + 3] = v.w;
    }
    sh[0][r] = hprev[(size_t)b * MHW + mi * HH + r];
    __syncthreads();

    int Tm = TT >> mi;
    float* hout = hmod + c_hmod_off[mi];
    float u_next = xwb[(size_t)b * MHW + mi * HH + r];  // t=0
    for (int k = 0; k < Tm; ++k) {
        int cur = k & 1;
        float u = u_next;
        if (k + 1 < Tm) {
            int t1 = (k + 1) << mi;
            u_next = xwb[(size_t)(t1 * BB + b) * MHW + mi * HH + r];
        }
        float a0 = 0.f, a1 = 0.f, a2 = 0.f, a3 = 0.f;
#pragma unroll
        for (int c = 0; c < 128; c += 4) {
            a0 += A[c] * sh[cur][c];
            a1 += A[c + 1] * sh[cur][c + 1];
            a2 += A[c + 2] * sh[cur][c + 2];
            a3 += A[c + 3] * sh[cur][c + 3];
        }
        float hn = (a0 + a1) + (a2 + a3) + u;
        hout[((size_t)k * BB + b) * HH + r] = hn;
        sh[cur ^ 1][r] = hn;
        __syncthreads();
    }
}

// ---------------------------------------------------------------------------
// K_out: out[t][b][j*H + h] = Hmod[j][t>>j][b][h]; h_last for t==T-1
// ---------------------------------------------------------------------------
__global__ __launch_bounds__(256) void k_out(const float* __restrict__ hmod,
                                             float* __restrict__ out) {
    int b = blockIdx.x, t = blockIdx.y;
    int tid = threadIdx.x;
    int i = tid * 4;
    int j = i >> 7;
    int k = t >> j;
    const float4 v = *reinterpret_cast<const float4*>(
        &hmod[c_hmod_off[j] + ((size_t)k * BB + b) * HH + (i & 127)]);
    *reinterpret_cast<float4*>(&out[((size_t)t * BB + b) * MHW + i]) = v;
    if (t == TT - 1) {
        *reinterpret_cast<float4*>(
            &out[(size_t)TT * BB * MHW + (size_t)b * MHW + i]) = v;
    }
}

// ---------------------------------------------------------------------------
extern "C" void kernel_launch(void* const* d_in, const int* in_sizes, int n_in,
                              void* d_out, int out_size, void* d_ws, size_t ws_size,
                              hipStream_t stream) {
    const float* x = (const float*)d_in[0];
    const float* hprev = (const float*)d_in[1];
    const float* Wxh = (const float*)d_in[2];
    const float* Whh = (const float*)d_in[3];
    const float* bh = (const float*)d_in[4];
    float* out = (float*)d_out;

    float* xwb = out;            // scratch: xW + bh + u, overwritten by k_out
    float* hmod = (float*)d_ws;  // 8,355,840 floats = 33.4 MB

    k_xw<<<dim3(8, 256), 256, 0, stream>>>(x, Wxh, bh, xwb);

    for (int mi = 7; mi >= 0; --mi) {
        if (mi < 7)
            k_u<<<dim3(TT >> mi), 256, 0, stream>>>(Whh, hprev, hmod, xwb, mi);
        k_phase<<<128, 128, 0, stream>>>(Whh, hprev, xwb, hmod, mi);
    }

    k_out<<<dim3(128, 256), 256, 0, stream>>>(hmod, out);
}

// Round 4
// 539.899 us; speedup vs baseline: 2.7118x; 1.1266x over previous
//
#include <hip/hip_runtime.h>
#include <hip/hip_bf16.h>

// Clockwork RNN, hierarchical decomposition + bf16 MFMA GEMMs.
// Round 4: k_phase rewritten as register-resident-A MFMA scan.
//   8 blocks x 16 batches; wave w owns rows [32w,32w+32); A as MFMA frags in
//   VGPRs; H state ping-pongs through swizzled LDS; U prefetched 2 steps ahead;
//   one barrier per serial step.

#define TT 256
#define BB 128
#define INW 512
#define HH 128
#define MHW 1024

typedef __bf16 bf16x8 __attribute__((ext_vector_type(8)));
typedef float f32x4 __attribute__((ext_vector_type(4)));

__constant__ unsigned int c_hmod_off[8] = {
    0u, 4194304u, 6291456u, 7340032u, 7864320u, 8126464u, 8257536u, 8323072u};

__device__ __forceinline__ int active_thr(int t) {
    int ma = (t == 0) ? 8 : min(__ffs(t), 8);
    return ma * HH;
}

__device__ __forceinline__ unsigned short f2bf(float f) {
    union { float f; unsigned int u; } v{f};
    unsigned int r = v.u + 0x7FFFu + ((v.u >> 16) & 1u);  // RNE
    return (unsigned short)(r >> 16);
}
__device__ __forceinline__ unsigned int pack2(float lo, float hi) {
    return (unsigned int)f2bf(lo) | ((unsigned int)f2bf(hi) << 16);
}

#define TILE_B 16384  // one [128 rows][64 k] bf16 tile image in LDS

// Batch-load a [128][64] f32 tile: 8 independent float4 per thread.
__device__ __forceinline__ void stage_load(float4 (&v)[8],
                                           const float* __restrict__ src,
                                           int stride, int tid) {
    int k4 = (tid & 15) * 4;
    int r0 = tid >> 4;
#pragma unroll
    for (int p = 0; p < 8; ++p)
        v[p] = *reinterpret_cast<const float4*>(src + (size_t)(p * 16 + r0) * stride + k4);
}

// Convert + write the staged tile into LDS (bf16, XOR-swizzled rows).
__device__ __forceinline__ void stage_write(char* dst, const float4 (&v)[8], int tid) {
    int k8 = (tid & 15) * 8;  // byte offset of this thread's 4 bf16
    int r0 = tid >> 4;
#pragma unroll
    for (int p = 0; p < 8; ++p) {
        int row = p * 16 + r0;
        ushort4 b;
        b.x = f2bf(v[p].x); b.y = f2bf(v[p].y);
        b.z = f2bf(v[p].z); b.w = f2bf(v[p].w);
        int off = (row * 128 + k8) ^ ((row & 7) << 4);
        *reinterpret_cast<ushort4*>(dst + off) = b;
    }
}

// Read one 16x32 bf16 fragment (8 bf16) from a swizzled tile.
__device__ __forceinline__ bf16x8 frag_ld(const char* tile, int row, int ks, int lane) {
    int off = (row * 128 + ks * 64 + (lane >> 4) * 16) ^ ((row & 7) << 4);
    return *reinterpret_cast<const bf16x8*>(tile + off);
}

// 128x128x64 MFMA block: A-tile x B-tile -> acc
__device__ __forceinline__ void mfma_tile(const char* sA, const char* sB,
                                          f32x4 (&acc)[4][4], int lane,
                                          int wr, int wc) {
#pragma unroll
    for (int ks = 0; ks < 2; ++ks) {
        bf16x8 fa[4], fb[4];
#pragma unroll
        for (int i = 0; i < 4; ++i) {
            fa[i] = frag_ld(sA, wr + i * 16 + (lane & 15), ks, lane);
            fb[i] = frag_ld(sB, wc + i * 16 + (lane & 15), ks, lane);
        }
#pragma unroll
        for (int i = 0; i < 4; ++i)
#pragma unroll
            for (int j = 0; j < 4; ++j)
                acc[i][j] = __builtin_amdgcn_mfma_f32_16x16x32_bf16(
                    fa[i], fb[j], acc[i][j], 0, 0, 0);
    }
}

// ---------------------------------------------------------------------------
// K_xw: xwb[t][b][mi*H + r] = sum_i x[t][b][i]*Wxh[mi*H+r][i] + bh[...]
// ---------------------------------------------------------------------------
__global__ __launch_bounds__(256) void k_xw(const float* __restrict__ x,
                                            const float* __restrict__ Wxh,
                                            const float* __restrict__ bh,
                                            float* __restrict__ xwb) {
    int mi = blockIdx.x, t = blockIdx.y;
    if (mi * HH >= active_thr(t)) return;

    __shared__ char lds[4 * TILE_B];  // W0 X0 | W1 X1
    int tid = threadIdx.x, lane = tid & 63, wid = tid >> 6;
    int wr = (wid >> 1) * 64, wc = (wid & 1) * 64;
    const float* Wbase = Wxh + (size_t)(mi * HH) * INW;
    const float* Xbase = x + (size_t)t * BB * INW;

    f32x4 acc[4][4] = {};
    float4 vW[8], vX[8];
    stage_load(vW, Wbase, INW, tid);
    stage_load(vX, Xbase, INW, tid);
    stage_write(lds, vW, tid);
    stage_write(lds + TILE_B, vX, tid);

    for (int it = 0; it < 8; ++it) {
        int cur = it & 1;
        __syncthreads();
        if (it < 7) {
            stage_load(vW, Wbase + (it + 1) * 64, INW, tid);
            stage_load(vX, Xbase + (it + 1) * 64, INW, tid);
        }
        mfma_tile(lds + cur * 2 * TILE_B, lds + cur * 2 * TILE_B + TILE_B,
                  acc, lane, wr, wc);
        if (it < 7) {
            stage_write(lds + (cur ^ 1) * 2 * TILE_B, vW, tid);
            stage_write(lds + (cur ^ 1) * 2 * TILE_B + TILE_B, vX, tid);
        }
    }
#pragma unroll
    for (int i = 0; i < 4; ++i) {
        int rbase = wr + i * 16 + (lane >> 4) * 4;
        float4 bias = *reinterpret_cast<const float4*>(&bh[mi * HH + rbase]);
#pragma unroll
        for (int j = 0; j < 4; ++j) {
            int b = wc + j * 16 + (lane & 15);
            float4 v = make_float4(acc[i][j][0] + bias.x, acc[i][j][1] + bias.y,
                                   acc[i][j][2] + bias.z, acc[i][j][3] + bias.w);
            *reinterpret_cast<float4*>(
                &xwb[(size_t)(t * BB + b) * MHW + mi * HH + rbase]) = v;
        }
    }
}

// ---------------------------------------------------------------------------
// K_u: xwb[t][b][mi*H+r] += sum_{j>mi} Whh[mi*H+r][j*H+c] * h_j[b][c]
// ---------------------------------------------------------------------------
__global__ __launch_bounds__(256) void k_u(const float* __restrict__ Whh,
                                           const float* __restrict__ hprev,
                                           const float* __restrict__ hmod,
                                           float* __restrict__ xwb, int mi) {
    int k = blockIdx.x;
    int t = k << mi;
    __shared__ char lds[4 * TILE_B];  // A0 H0 | A1 H1
    int tid = threadIdx.x, lane = tid & 63, wid = tid >> 6;
    int wr = (wid >> 1) * 64, wc = (wid & 1) * 64;

    int ntile = 2 * (7 - mi);
    auto srcs = [&](int tt, const float*& pa, const float*& ph, int& hstr) {
        int j = mi + 1 + (tt >> 1);
        int c0 = (tt & 1) * 64;
        pa = Whh + (size_t)(mi * HH) * MHW + j * HH + c0;
        if (k == 0) {
            ph = hprev + j * HH + c0;
            hstr = MHW;
        } else {
            int g = (t - 1) >> j;
            ph = hmod + c_hmod_off[j] + (size_t)g * BB * HH + c0;
            hstr = HH;
        }
    };

    f32x4 acc[4][4] = {};
    float4 vA[8], vH[8];
    const float *pa, *ph;
    int hstr;
    srcs(0, pa, ph, hstr);
    stage_load(vA, pa, MHW, tid);
    stage_load(vH, ph, hstr, tid);
    stage_write(lds, vA, tid);
    stage_write(lds + TILE_B, vH, tid);

    for (int tt = 0; tt < ntile; ++tt) {
        int cur = tt & 1;
        __syncthreads();
        if (tt + 1 < ntile) {
            srcs(tt + 1, pa, ph, hstr);
            stage_load(vA, pa, MHW, tid);
            stage_load(vH, ph, hstr, tid);
        }
        mfma_tile(lds + cur * 2 * TILE_B, lds + cur * 2 * TILE_B + TILE_B,
                  acc, lane, wr, wc);
        if (tt + 1 < ntile) {
            stage_write(lds + (cur ^ 1) * 2 * TILE_B, vA, tid);
            stage_write(lds + (cur ^ 1) * 2 * TILE_B + TILE_B, vH, tid);
        }
    }
#pragma unroll
    for (int i = 0; i < 4; ++i) {
        int rbase = wr + i * 16 + (lane >> 4) * 4;
#pragma unroll
        for (int j = 0; j < 4; ++j) {
            int b = wc + j * 16 + (lane & 15);
            float4* p = reinterpret_cast<float4*>(
                &xwb[(size_t)(t * BB + b) * MHW + mi * HH + rbase]);
            float4 v = *p;
            v.x += acc[i][j][0]; v.y += acc[i][j][1];
            v.z += acc[i][j][2]; v.w += acc[i][j][3];
            *p = v;
        }
    }
}

// ---------------------------------------------------------------------------
// K_phase v2: MFMA scan. grid 8 blocks (16 batches), 256 threads (4 waves).
// Wave w owns rows [32w, 32w+32). A kept as bf16 MFMA A-frags in registers.
// H ping-pongs through LDS as [b][r] bf16 (XOR-swizzled), 1 barrier/step.
// ---------------------------------------------------------------------------
__global__ __launch_bounds__(256) void k_phase(const float* __restrict__ Whh,
                                               const float* __restrict__ hprev,
                                               const float* __restrict__ xwb,
                                               float* __restrict__ hmod, int mi) {
    int b0 = blockIdx.x * 16;
    int tid = threadIdx.x, lane = tid & 63, wid = tid >> 6;
    int l15 = lane & 15, g = lane >> 4;
    __shared__ char sH[2][16 * 256];  // [buf][b][r*2 bytes], swizzled

    // --- A fragments Af[m][kf]: rows r = wid*32 + m*16 + l15 ---
    bf16x8 Af[2][4];
    {
        const float* Ab = Whh + (size_t)(mi * HH) * MHW + mi * HH;
#pragma unroll
        for (int m = 0; m < 2; ++m) {
            const float* row = Ab + (size_t)(wid * 32 + m * 16 + l15) * MHW;
#pragma unroll
            for (int kf = 0; kf < 4; ++kf) {
                float4 v0 = *reinterpret_cast<const float4*>(row + kf * 32 + g * 8);
                float4 v1 = *reinterpret_cast<const float4*>(row + kf * 32 + g * 8 + 4);
                union { bf16x8 v; unsigned int w[4]; } u;
                u.w[0] = pack2(v0.x, v0.y); u.w[1] = pack2(v0.z, v0.w);
                u.w[2] = pack2(v1.x, v1.y); u.w[3] = pack2(v1.z, v1.w);
                Af[m][kf] = u.v;
            }
        }
    }
    // --- initial H into buf 0: thread t -> batch t>>4, elems (t&15)*8.. ---
    {
        int b = tid >> 4, r8 = (tid & 15) * 8;
        const float* hp = hprev + (size_t)(b0 + b) * MHW + mi * HH + r8;
        float4 v0 = *reinterpret_cast<const float4*>(hp);
        float4 v1 = *reinterpret_cast<const float4*>(hp + 4);
        uint4 pk;
        pk.x = pack2(v0.x, v0.y); pk.y = pack2(v0.z, v0.w);
        pk.z = pack2(v1.x, v1.y); pk.w = pack2(v1.z, v1.w);
        int off = (b * 256 + r8 * 2) ^ ((b & 7) << 4);
        *reinterpret_cast<uint4*>(&sH[0][0] + off) = pk;
    }

    // per-lane constant offsets
    int roff[4], woff[2];
#pragma unroll
    for (int kf = 0; kf < 4; ++kf)
        roff[kf] = (l15 * 256 + kf * 64 + g * 16) ^ ((l15 & 7) << 4);
#pragma unroll
    for (int m = 0; m < 2; ++m)
        woff[m] = (l15 * 256 + (wid * 32 + m * 16 + g * 4) * 2) ^ ((l15 & 7) << 4);

    const float* xwb_lane = xwb + (size_t)(b0 + l15) * MHW + mi * HH + wid * 32 + g * 4;
    float* hmod_lane = hmod + c_hmod_off[mi] + (size_t)(b0 + l15) * HH + wid * 32 + g * 4;
    int Tm = TT >> mi;

    // U prefetch slots (distance 2): uA = step 0, uB = step 1
    float4 uA[2], uB[2];
#pragma unroll
    for (int m = 0; m < 2; ++m) {
        uA[m] = *reinterpret_cast<const float4*>(xwb_lane + m * 16);
        uB[m] = *reinterpret_cast<const float4*>(
            xwb_lane + (size_t)(1 << mi) * BB * MHW + m * 16);
    }
    __syncthreads();

#define PHASE_STEP(KK, USLOT)                                                   \
    do {                                                                        \
        int cur = (KK) & 1;                                                     \
        bf16x8 Bf[4];                                                           \
        _Pragma("unroll") for (int kf = 0; kf < 4; ++kf)                        \
            Bf[kf] = *reinterpret_cast<const bf16x8*>(&sH[cur][0] + roff[kf]);  \
        f32x4 acc[2];                                                           \
        _Pragma("unroll") for (int m = 0; m < 2; ++m) {                         \
            acc[m][0] = USLOT[m].x; acc[m][1] = USLOT[m].y;                     \
            acc[m][2] = USLOT[m].z; acc[m][3] = USLOT[m].w;                     \
        }                                                                       \
        int t2 = min((KK) + 2, Tm - 1) << mi;                                   \
        _Pragma("unroll") for (int m = 0; m < 2; ++m)                           \
            USLOT[m] = *reinterpret_cast<const float4*>(                        \
                xwb_lane + (size_t)t2 * BB * MHW + m * 16);                     \
        _Pragma("unroll") for (int kf = 0; kf < 4; ++kf)                        \
            _Pragma("unroll") for (int m = 0; m < 2; ++m)                       \
                acc[m] = __builtin_amdgcn_mfma_f32_16x16x32_bf16(               \
                    Af[m][kf], Bf[kf], acc[m], 0, 0, 0);                        \
        _Pragma("unroll") for (int m = 0; m < 2; ++m) {                         \
            uint2 pk;                                                           \
            pk.x = pack2(acc[m][0], acc[m][1]);                                 \
            pk.y = pack2(acc[m][2], acc[m][3]);                                 \
            *reinterpret_cast<uint2*>(&sH[cur ^ 1][0] + woff[m]) = pk;          \
            *reinterpret_cast<f32x4*>(                                          \
                hmod_lane + (size_t)(KK)*BB * HH + m * 16) = acc[m];            \
        }                                                                       \
        __syncthreads();                                                        \
    } while (0)

    for (int k = 0; k < Tm; k += 2) {
        PHASE_STEP(k, uA);
        PHASE_STEP(k + 1, uB);
    }
#undef PHASE_STEP
}

// ---------------------------------------------------------------------------
// K_out: out[t][b][j*H + h] = Hmod[j][t>>j][b][h]; h_last for t==T-1
// ---------------------------------------------------------------------------
__global__ __launch_bounds__(256) void k_out(const float* __restrict__ hmod,
                                             float* __restrict__ out) {
    int b = blockIdx.x, t = blockIdx.y;
    int tid = threadIdx.x;
    int i = tid * 4;
    int j = i >> 7;
    int k = t >> j;
    const float4 v = *reinterpret_cast<const float4*>(
        &hmod[c_hmod_off[j] + ((size_t)k * BB + b) * HH + (i & 127)]);
    *reinterpret_cast<float4*>(&out[((size_t)t * BB + b) * MHW + i]) = v;
    if (t == TT - 1) {
        *reinterpret_cast<float4*>(
            &out[(size_t)TT * BB * MHW + (size_t)b * MHW + i]) = v;
    }
}

// ---------------------------------------------------------------------------
extern "C" void kernel_launch(void* const* d_in, const int* in_sizes, int n_in,
                              void* d_out, int out_size, void* d_ws, size_t ws_size,
                              hipStream_t stream) {
    const float* x = (const float*)d_in[0];
    const float* hprev = (const float*)d_in[1];
    const float* Wxh = (const float*)d_in[2];
    const float* Whh = (const float*)d_in[3];
    const float* bh = (const float*)d_in[4];
    float* out = (float*)d_out;

    float* xwb = out;            // scratch: xW + bh + u, overwritten by k_out
    float* hmod = (float*)d_ws;  // 8,355,840 floats = 33.4 MB

    k_xw<<<dim3(8, 256), 256, 0, stream>>>(x, Wxh, bh, xwb);

    for (int mi = 7; mi >= 0; --mi) {
        if (mi < 7)
            k_u<<<dim3(TT >> mi), 256, 0, stream>>>(Whh, hprev, hmod, xwb, mi);
        k_phase<<<8, 256, 0, stream>>>(Whh, hprev, xwb, hmod, mi);
    }

    k_out<<<dim3(128, 256), 256, 0, stream>>>(hmod, out);
}

// Round 5
// 518.876 us; speedup vs baseline: 2.8217x; 1.0405x over previous
//
#include <hip/hip_runtime.h>
#include <hip/hip_bf16.h>

// Clockwork RNN, hierarchical decomposition + bf16 MFMA GEMMs.
// Round 5: k_phase serial step uses raw s_barrier + lgkmcnt-only wait
// (no vmcnt drain => hmod stores and U prefetch loads stay in flight
// across barriers), and split MFMA accumulation chains (2-deep, not 4).

#define TT 256
#define BB 128
#define INW 512
#define HH 128
#define MHW 1024

typedef __bf16 bf16x8 __attribute__((ext_vector_type(8)));
typedef float f32x4 __attribute__((ext_vector_type(4)));

__constant__ unsigned int c_hmod_off[8] = {
    0u, 4194304u, 6291456u, 7340032u, 7864320u, 8126464u, 8257536u, 8323072u};

__device__ __forceinline__ int active_thr(int t) {
    int ma = (t == 0) ? 8 : min(__ffs(t), 8);
    return ma * HH;
}

__device__ __forceinline__ unsigned short f2bf(float f) {
    union { float f; unsigned int u; } v{f};
    unsigned int r = v.u + 0x7FFFu + ((v.u >> 16) & 1u);  // RNE
    return (unsigned short)(r >> 16);
}
__device__ __forceinline__ unsigned int pack2(float lo, float hi) {
    return (unsigned int)f2bf(lo) | ((unsigned int)f2bf(hi) << 16);
}

#define TILE_B 16384  // one [128 rows][64 k] bf16 tile image in LDS

// Batch-load a [128][64] f32 tile: 8 independent float4 per thread.
__device__ __forceinline__ void stage_load(float4 (&v)[8],
                                           const float* __restrict__ src,
                                           int stride, int tid) {
    int k4 = (tid & 15) * 4;
    int r0 = tid >> 4;
#pragma unroll
    for (int p = 0; p < 8; ++p)
        v[p] = *reinterpret_cast<const float4*>(src + (size_t)(p * 16 + r0) * stride + k4);
}

// Convert + write the staged tile into LDS (bf16, XOR-swizzled rows).
__device__ __forceinline__ void stage_write(char* dst, const float4 (&v)[8], int tid) {
    int k8 = (tid & 15) * 8;  // byte offset of this thread's 4 bf16
    int r0 = tid >> 4;
#pragma unroll
    for (int p = 0; p < 8; ++p) {
        int row = p * 16 + r0;
        ushort4 b;
        b.x = f2bf(v[p].x); b.y = f2bf(v[p].y);
        b.z = f2bf(v[p].z); b.w = f2bf(v[p].w);
        int off = (row * 128 + k8) ^ ((row & 7) << 4);
        *reinterpret_cast<ushort4*>(dst + off) = b;
    }
}

// Read one 16x32 bf16 fragment (8 bf16) from a swizzled tile.
__device__ __forceinline__ bf16x8 frag_ld(const char* tile, int row, int ks, int lane) {
    int off = (row * 128 + ks * 64 + (lane >> 4) * 16) ^ ((row & 7) << 4);
    return *reinterpret_cast<const bf16x8*>(tile + off);
}

// 128x128x64 MFMA block: A-tile x B-tile -> acc
__device__ __forceinline__ void mfma_tile(const char* sA, const char* sB,
                                          f32x4 (&acc)[4][4], int lane,
                                          int wr, int wc) {
#pragma unroll
    for (int ks = 0; ks < 2; ++ks) {
        bf16x8 fa[4], fb[4];
#pragma unroll
        for (int i = 0; i < 4; ++i) {
            fa[i] = frag_ld(sA, wr + i * 16 + (lane & 15), ks, lane);
            fb[i] = frag_ld(sB, wc + i * 16 + (lane & 15), ks, lane);
        }
#pragma unroll
        for (int i = 0; i < 4; ++i)
#pragma unroll
            for (int j = 0; j < 4; ++j)
                acc[i][j] = __builtin_amdgcn_mfma_f32_16x16x32_bf16(
                    fa[i], fb[j], acc[i][j], 0, 0, 0);
    }
}

// ---------------------------------------------------------------------------
// K_xw: xwb[t][b][mi*H + r] = sum_i x[t][b][i]*Wxh[mi*H+r][i] + bh[...]
// ---------------------------------------------------------------------------
__global__ __launch_bounds__(256) void k_xw(const float* __restrict__ x,
                                            const float* __restrict__ Wxh,
                                            const float* __restrict__ bh,
                                            float* __restrict__ xwb) {
    int mi = blockIdx.x, t = blockIdx.y;
    if (mi * HH >= active_thr(t)) return;

    __shared__ char lds[4 * TILE_B];  // W0 X0 | W1 X1
    int tid = threadIdx.x, lane = tid & 63, wid = tid >> 6;
    int wr = (wid >> 1) * 64, wc = (wid & 1) * 64;
    const float* Wbase = Wxh + (size_t)(mi * HH) * INW;
    const float* Xbase = x + (size_t)t * BB * INW;

    f32x4 acc[4][4] = {};
    float4 vW[8], vX[8];
    stage_load(vW, Wbase, INW, tid);
    stage_load(vX, Xbase, INW, tid);
    stage_write(lds, vW, tid);
    stage_write(lds + TILE_B, vX, tid);

    for (int it = 0; it < 8; ++it) {
        int cur = it & 1;
        __syncthreads();
        if (it < 7) {
            stage_load(vW, Wbase + (it + 1) * 64, INW, tid);
            stage_load(vX, Xbase + (it + 1) * 64, INW, tid);
        }
        mfma_tile(lds + cur * 2 * TILE_B, lds + cur * 2 * TILE_B + TILE_B,
                  acc, lane, wr, wc);
        if (it < 7) {
            stage_write(lds + (cur ^ 1) * 2 * TILE_B, vW, tid);
            stage_write(lds + (cur ^ 1) * 2 * TILE_B + TILE_B, vX, tid);
        }
    }
#pragma unroll
    for (int i = 0; i < 4; ++i) {
        int rbase = wr + i * 16 + (lane >> 4) * 4;
        float4 bias = *reinterpret_cast<const float4*>(&bh[mi * HH + rbase]);
#pragma unroll
        for (int j = 0; j < 4; ++j) {
            int b = wc + j * 16 + (lane & 15);
            float4 v = make_float4(acc[i][j][0] + bias.x, acc[i][j][1] + bias.y,
                                   acc[i][j][2] + bias.z, acc[i][j][3] + bias.w);
            *reinterpret_cast<float4*>(
                &xwb[(size_t)(t * BB + b) * MHW + mi * HH + rbase]) = v;
        }
    }
}

// ---------------------------------------------------------------------------
// K_u: xwb[t][b][mi*H+r] += sum_{j>mi} Whh[mi*H+r][j*H+c] * h_j[b][c]
// ---------------------------------------------------------------------------
__global__ __launch_bounds__(256) void k_u(const float* __restrict__ Whh,
                                           const float* __restrict__ hprev,
                                           const float* __restrict__ hmod,
                                           float* __restrict__ xwb, int mi) {
    int k = blockIdx.x;
    int t = k << mi;
    __shared__ char lds[4 * TILE_B];  // A0 H0 | A1 H1
    int tid = threadIdx.x, lane = tid & 63, wid = tid >> 6;
    int wr = (wid >> 1) * 64, wc = (wid & 1) * 64;

    int ntile = 2 * (7 - mi);
    auto srcs = [&](int tt, const float*& pa, const float*& ph, int& hstr) {
        int j = mi + 1 + (tt >> 1);
        int c0 = (tt & 1) * 64;
        pa = Whh + (size_t)(mi * HH) * MHW + j * HH + c0;
        if (k == 0) {
            ph = hprev + j * HH + c0;
            hstr = MHW;
        } else {
            int g = (t - 1) >> j;
            ph = hmod + c_hmod_off[j] + (size_t)g * BB * HH + c0;
            hstr = HH;
        }
    };

    f32x4 acc[4][4] = {};
    float4 vA[8], vH[8];
    const float *pa, *ph;
    int hstr;
    srcs(0, pa, ph, hstr);
    stage_load(vA, pa, MHW, tid);
    stage_load(vH, ph, hstr, tid);
    stage_write(lds, vA, tid);
    stage_write(lds + TILE_B, vH, tid);

    for (int tt = 0; tt < ntile; ++tt) {
        int cur = tt & 1;
        __syncthreads();
        if (tt + 1 < ntile) {
            srcs(tt + 1, pa, ph, hstr);
            stage_load(vA, pa, MHW, tid);
            stage_load(vH, ph, hstr, tid);
        }
        mfma_tile(lds + cur * 2 * TILE_B, lds + cur * 2 * TILE_B + TILE_B,
                  acc, lane, wr, wc);
        if (tt + 1 < ntile) {
            stage_write(lds + (cur ^ 1) * 2 * TILE_B, vA, tid);
            stage_write(lds + (cur ^ 1) * 2 * TILE_B + TILE_B, vH, tid);
        }
    }
#pragma unroll
    for (int i = 0; i < 4; ++i) {
        int rbase = wr + i * 16 + (lane >> 4) * 4;
#pragma unroll
        for (int j = 0; j < 4; ++j) {
            int b = wc + j * 16 + (lane & 15);
            float4* p = reinterpret_cast<float4*>(
                &xwb[(size_t)(t * BB + b) * MHW + mi * HH + rbase]);
            float4 v = *p;
            v.x += acc[i][j][0]; v.y += acc[i][j][1];
            v.z += acc[i][j][2]; v.w += acc[i][j][3];
            *p = v;
        }
    }
}

// ---------------------------------------------------------------------------
// K_phase v3: MFMA scan, raw-barrier (lgkmcnt-only) per step.
// grid 8 blocks (16 batches), 256 threads (4 waves); wave w owns rows
// [32w,32w+32); A as bf16 MFMA A-frags in VGPRs; H ping-pongs through
// swizzled LDS; U prefetched 2 steps ahead; global ops never drained in-loop.
// ---------------------------------------------------------------------------
__global__ __launch_bounds__(256) void k_phase(const float* __restrict__ Whh,
                                               const float* __restrict__ hprev,
                                               const float* __restrict__ xwb,
                                               float* __restrict__ hmod, int mi) {
    int b0 = blockIdx.x * 16;
    int tid = threadIdx.x, lane = tid & 63, wid = tid >> 6;
    int l15 = lane & 15, g = lane >> 4;
    __shared__ char sH[2][16 * 256];  // [buf][b][r*2 bytes], swizzled

    // --- A fragments Af[m][kf]: rows r = wid*32 + m*16 + l15 ---
    bf16x8 Af[2][4];
    {
        const float* Ab = Whh + (size_t)(mi * HH) * MHW + mi * HH;
#pragma unroll
        for (int m = 0; m < 2; ++m) {
            const float* row = Ab + (size_t)(wid * 32 + m * 16 + l15) * MHW;
#pragma unroll
            for (int kf = 0; kf < 4; ++kf) {
                float4 v0 = *reinterpret_cast<const float4*>(row + kf * 32 + g * 8);
                float4 v1 = *reinterpret_cast<const float4*>(row + kf * 32 + g * 8 + 4);
                union { bf16x8 v; unsigned int w[4]; } u;
                u.w[0] = pack2(v0.x, v0.y); u.w[1] = pack2(v0.z, v0.w);
                u.w[2] = pack2(v1.x, v1.y); u.w[3] = pack2(v1.z, v1.w);
                Af[m][kf] = u.v;
            }
        }
    }
    // --- initial H into buf 0 ---
    {
        int b = tid >> 4, r8 = (tid & 15) * 8;
        const float* hp = hprev + (size_t)(b0 + b) * MHW + mi * HH + r8;
        float4 v0 = *reinterpret_cast<const float4*>(hp);
        float4 v1 = *reinterpret_cast<const float4*>(hp + 4);
        uint4 pk;
        pk.x = pack2(v0.x, v0.y); pk.y = pack2(v0.z, v0.w);
        pk.z = pack2(v1.x, v1.y); pk.w = pack2(v1.z, v1.w);
        int off = (b * 256 + r8 * 2) ^ ((b & 7) << 4);
        *reinterpret_cast<uint4*>(&sH[0][0] + off) = pk;
    }

    // per-lane constant offsets
    int roff[4], woff[2];
#pragma unroll
    for (int kf = 0; kf < 4; ++kf)
        roff[kf] = (l15 * 256 + kf * 64 + g * 16) ^ ((l15 & 7) << 4);
#pragma unroll
    for (int m = 0; m < 2; ++m)
        woff[m] = (l15 * 256 + (wid * 32 + m * 16 + g * 4) * 2) ^ ((l15 & 7) << 4);

    const float* xwb_lane = xwb + (size_t)(b0 + l15) * MHW + mi * HH + wid * 32 + g * 4;
    float* hmod_lane = hmod + c_hmod_off[mi] + (size_t)(b0 + l15) * HH + wid * 32 + g * 4;
    int Tm = TT >> mi;

    // U prefetch slots (distance 2): uA = step 0, uB = step 1
    float4 uA[2], uB[2];
#pragma unroll
    for (int m = 0; m < 2; ++m) {
        uA[m] = *reinterpret_cast<const float4*>(xwb_lane + m * 16);
        uB[m] = *reinterpret_cast<const float4*>(
            xwb_lane + (size_t)(1 << mi) * BB * MHW + m * 16);
    }
    __syncthreads();

// Raw barrier: LDS-visibility wait only; global loads/stores stay in flight.
#define SYNC_LDS()                                              \
    do {                                                        \
        asm volatile("s_waitcnt lgkmcnt(0)" ::: "memory");      \
        __builtin_amdgcn_sched_barrier(0);                      \
        __builtin_amdgcn_s_barrier();                           \
        __builtin_amdgcn_sched_barrier(0);                      \
    } while (0)

#define PHASE_STEP(KK, USLOT)                                                   \
    do {                                                                        \
        int cur = (KK) & 1;                                                     \
        bf16x8 Bf[4];                                                           \
        _Pragma("unroll") for (int kf = 0; kf < 4; ++kf)                        \
            Bf[kf] = *reinterpret_cast<const bf16x8*>(&sH[cur][0] + roff[kf]);  \
        f32x4 acc[2], acc2[2];                                                  \
        _Pragma("unroll") for (int m = 0; m < 2; ++m) {                         \
            acc[m][0] = USLOT[m].x; acc[m][1] = USLOT[m].y;                     \
            acc[m][2] = USLOT[m].z; acc[m][3] = USLOT[m].w;                     \
            acc2[m] = (f32x4){0.f, 0.f, 0.f, 0.f};                              \
        }                                                                       \
        int t2 = min((KK) + 2, Tm - 1) << mi;                                   \
        _Pragma("unroll") for (int m = 0; m < 2; ++m)                           \
            USLOT[m] = *reinterpret_cast<const float4*>(                        \
                xwb_lane + (size_t)t2 * BB * MHW + m * 16);                     \
        _Pragma("unroll") for (int m = 0; m < 2; ++m) {                         \
            acc[m] = __builtin_amdgcn_mfma_f32_16x16x32_bf16(                   \
                Af[m][0], Bf[0], acc[m], 0, 0, 0);                              \
            acc2[m] = __builtin_amdgcn_mfma_f32_16x16x32_bf16(                  \
                Af[m][2], Bf[2], acc2[m], 0, 0, 0);                             \
            acc[m] = __builtin_amdgcn_mfma_f32_16x16x32_bf16(                   \
                Af[m][1], Bf[1], acc[m], 0, 0, 0);                              \
            acc2[m] = __builtin_amdgcn_mfma_f32_16x16x32_bf16(                  \
                Af[m][3], Bf[3], acc2[m], 0, 0, 0);                             \
        }                                                                       \
        _Pragma("unroll") for (int m = 0; m < 2; ++m) {                         \
            acc[m] += acc2[m];                                                  \
            uint2 pk;                                                           \
            pk.x = pack2(acc[m][0], acc[m][1]);                                 \
            pk.y = pack2(acc[m][2], acc[m][3]);                                 \
            *reinterpret_cast<uint2*>(&sH[cur ^ 1][0] + woff[m]) = pk;          \
            *reinterpret_cast<f32x4*>(                                          \
                hmod_lane + (size_t)(KK)*BB * HH + m * 16) = acc[m];            \
        }                                                                       \
        SYNC_LDS();                                                             \
    } while (0)

    for (int k = 0; k < Tm; k += 2) {
        PHASE_STEP(k, uA);
        PHASE_STEP(k + 1, uB);
    }
#undef PHASE_STEP
#undef SYNC_LDS
}

// ---------------------------------------------------------------------------
// K_out: out[t][b][j*H + h] = Hmod[j][t>>j][b][h]; h_last for t==T-1
// ---------------------------------------------------------------------------
__global__ __launch_bounds__(256) void k_out(const float* __restrict__ hmod,
                                             float* __restrict__ out) {
    int b = blockIdx.x, t = blockIdx.y;
    int tid = threadIdx.x;
    int i = tid * 4;
    int j = i >> 7;
    int k = t >> j;
    const float4 v = *reinterpret_cast<const float4*>(
        &hmod[c_hmod_off[j] + ((size_t)k * BB + b) * HH + (i & 127)]);
    *reinterpret_cast<float4*>(&out[((size_t)t * BB + b) * MHW + i]) = v;
    if (t == TT - 1) {
        *reinterpret_cast<float4*>(
            &out[(size_t)TT * BB * MHW + (size_t)b * MHW + i]) = v;
    }
}

// ---------------------------------------------------------------------------
extern "C" void kernel_launch(void* const* d_in, const int* in_sizes, int n_in,
                              void* d_out, int out_size, void* d_ws, size_t ws_size,
                              hipStream_t stream) {
    const float* x = (const float*)d_in[0];
    const float* hprev = (const float*)d_in[1];
    const float* Wxh = (const float*)d_in[2];
    const float* Whh = (const float*)d_in[3];
    const float* bh = (const float*)d_in[4];
    float* out = (float*)d_out;

    float* xwb = out;            // scratch: xW + bh + u, overwritten by k_out
    float* hmod = (float*)d_ws;  // 8,355,840 floats = 33.4 MB

    k_xw<<<dim3(8, 256), 256, 0, stream>>>(x, Wxh, bh, xwb);

    for (int mi = 7; mi >= 0; --mi) {
        if (mi < 7)
            k_u<<<dim3(TT >> mi), 256, 0, stream>>>(Whh, hprev, hmod, xwb, mi);
        k_phase<<<8, 256, 0, stream>>>(Whh, hprev, xwb, hmod, mi);
    }

    k_out<<<dim3(128, 256), 256, 0, stream>>>(hmod, out);
}